// Round 3
// baseline (151.192 us; speedup 1.0000x reference)
//
#include <hip/hip_runtime.h>

#define NSTEPS 10
constexpr int B_DIM = 256, T_DIM = 8192, D_DIM = 5;
constexpr int TILE  = 1024;   // items per block
constexpr int BLOCK = 256;    // threads per block; thread k owns items 4k..4k+3
constexpr long long GATE_N = (long long)B_DIM * 2 * T_DIM;   // 4,194,304
constexpr long long EXT_N  = GATE_N * D_DIM;                 // 20,971,520

// 10-step scan in f64 (bit-identical to rounds 1-2), f32 epilogue.
__device__ __forceinline__ float scan_score(double v0, double v1, double v2, double v3, double v4,
                                            const double* __restrict__ w) {
    float h[NSTEPS];
#pragma unroll
    for (int s = 0; s < NSTEPS; ++s) {
        double res = v0 * w[0];
        res = fma(v1, w[1], res);
        res = fma(v2, w[2], res);
        res = fma(v3, w[3], res);
        res = fma(v4, w[4], res);
        h[s] = (float)res;
        double q = floor(res * 0.1);
        double m = fma(q, -10.0, res);
        m = (m < 0.0)   ? m + 10.0 : m;
        m = (m >= 10.0) ? m - 10.0 : m;
        v4 = v3; v3 = v2; v2 = v1; v1 = v0; v0 = m;
    }
    float mean = 0.f;
#pragma unroll
    for (int s = 0; s < NSTEPS; ++s) mean += h[s];
    mean *= 0.1f;
    float ssd = 0.f;
#pragma unroll
    for (int s = 0; s < NSTEPS; ++s) { float d = h[s] - mean; ssd = fmaf(d, d, ssd); }
    float sd = sqrtf(ssd * (1.0f / 9.0f));
    return 1.0f / (1.0f + sd);
}

__global__ __launch_bounds__(BLOCK) void temple_gate_kernel(
    const float* __restrict__ x, const float* __restrict__ temple,
    const float* __restrict__ breath, float* __restrict__ out) {
    __shared__ float4 l4[TILE * D_DIM / 4];   // 20 KB, used only in mode 1

    const int k  = threadIdx.x;
    const int b  = blockIdx.x >> 3;           // 8 tiles per row
    const int t0 = (blockIdx.x & 7) * TILE;

    // ---- uniform scalars: mode + folded weights (f64, L2-hot broadcast loads) ----
    double s = 0.0;
#pragma unroll
    for (int d = 0; d < 5; ++d) s += (double)x[d];
    s = s / 5.0;
    double seed  = s - floor(s);
    double chaos = 3.5699456 * seed * (1.0 - seed);
    const int mode = (chaos > 0.7) ? 0 : ((chaos > 0.4) ? 1 : 2);
    double wm[5], wx[5];
#pragma unroll
    for (int d = 0; d < 5; ++d) {
        double a = 0.0, c = 0.0;
#pragma unroll
        for (int r = 0; r < 4; ++r) {
            double tv = (double)temple[r * 5 + d];
            a += (double)breath[r]     * tv;   // breath_main = breath[0:4]
            c += (double)breath[r + 1] * tv;   // breath_mirror = breath[1:5]
        }
        wm[d] = a; wx[d] = c;
    }
    if (blockIdx.x == 0 && k == 0) out[GATE_N + EXT_N] = (float)mode;

    // ---- item-aligned loads: thread k owns items 4k..4k+3 (20 floats, registers) ----
    const float4* __restrict__ src = (const float4*)(x + ((long long)b * T_DIM + t0) * D_DIM);
    float4 q[5];
#pragma unroll
    for (int j = 0; j < 5; ++j) q[j] = src[5 * k + j];
    float f[20];                              // f[m*5 + d], fully unrolled -> VGPRs
#pragma unroll
    for (int j = 0; j < 5; ++j) ((float4*)f)[j] = q[j];

    float* gate = out;
    float* ext  = out + GATE_N;
    const long long rowBase = (long long)b * (2 * T_DIM);

    if (mode == 1) {                          // stage tile for cross-thread flip
#pragma unroll
        for (int j = 0; j < 5; ++j) l4[5 * k + j] = q[j];
    }

    // ---- main ext: pure copy from registers (stores drain under the scans) ----
    {
        float4* dst = (float4*)(ext + (rowBase + t0) * D_DIM);
#pragma unroll
        for (int j = 0; j < 5; ++j) dst[5 * k + j] = q[j];
    }

    // ---- mirror ext ----
    if (mode == 0) {
        float4* dst = (float4*)(ext + (rowBase + T_DIM + t0) * D_DIM);
#pragma unroll
        for (int j = 0; j < 5; ++j)
            dst[5 * k + j] = make_float4(9.f - q[j].x, 9.f - q[j].y, 9.f - q[j].z, 9.f - q[j].w);
    } else if (mode == 2) {
        float4* dst = (float4*)(ext + (rowBase + T_DIM + t0) * D_DIM);
#pragma unroll
        for (int j = 0; j < 5; ++j) dst[5 * k + j] = q[j];
    } else {
        // mode 1: flipped tile; thread k's dest floats come from partner 255-k's items,
        // item-reversed, dim-preserved. Single barrier, conflict-free b128 partner read.
        __syncthreads();
        float pf[20];
#pragma unroll
        for (int j = 0; j < 5; ++j) ((float4*)pf)[j] = l4[5 * (255 - k) + j];
        float df[20];
#pragma unroll
        for (int c = 0; c < 4; ++c)
#pragma unroll
            for (int d = 0; d < 5; ++d) df[c * 5 + d] = pf[(3 - c) * 5 + d];
        float4* dst = (float4*)(ext + (rowBase + 2 * T_DIM - t0 - TILE) * D_DIM);
#pragma unroll
        for (int j = 0; j < 5; ++j)
            dst[5 * k + j] = make_float4(df[4 * j], df[4 * j + 1], df[4 * j + 2], df[4 * j + 3]);
    }

    // ---- scans straight from registers (no LDS dependency) ----
    float gm[4], gx[4];
#pragma unroll
    for (int m = 0; m < 4; ++m) {
        double v0 = f[m * 5 + 0], v1 = f[m * 5 + 1], v2 = f[m * 5 + 2],
               v3 = f[m * 5 + 3], v4 = f[m * 5 + 4];
        gm[m] = scan_score(v0, v1, v2, v3, v4, wm);
        if (mode == 0) { v0 = 9.0 - v0; v1 = 9.0 - v1; v2 = 9.0 - v2; v3 = 9.0 - v3; v4 = 9.0 - v4; }
        gx[m] = scan_score(v0, v1, v2, v3, v4, wx);
    }
    ((float4*)(gate + rowBase + t0))[k] = make_float4(gm[0], gm[1], gm[2], gm[3]);
    if (mode == 1) {
        ((float4*)(gate + rowBase + 2 * T_DIM - t0 - TILE))[255 - k] =
            make_float4(gx[3], gx[2], gx[1], gx[0]);
    } else {
        ((float4*)(gate + rowBase + T_DIM + t0))[k] = make_float4(gx[0], gx[1], gx[2], gx[3]);
    }
}

extern "C" void kernel_launch(void* const* d_in, const int* in_sizes, int n_in,
                              void* d_out, int out_size, void* d_ws, size_t ws_size,
                              hipStream_t stream) {
    const float* x      = (const float*)d_in[0];   // (256, 8192, 5) f32
    const float* temple = (const float*)d_in[1];   // (4, 5) f32
    const float* breath = (const float*)d_in[2];   // (5,) f32
    float* out = (float*)d_out;                    // [gate | extended_x | mode_code]

    const int blocks = (B_DIM * T_DIM) / TILE;     // 2048
    temple_gate_kernel<<<blocks, BLOCK, 0, stream>>>(x, temple, breath, out);
}

// Round 4
// 143.106 us; speedup vs baseline: 1.0565x; 1.0565x over previous
//
#include <hip/hip_runtime.h>

constexpr int B_DIM = 256, T_DIM = 8192;
constexpr long long GATE_N = (long long)B_DIM * 2 * T_DIM;   // 4,194,304
constexpr long long EXT_N  = GATE_N * 5;                     // 20,971,520

// One tiny block: fold breath@temple -> w[0..4] (main), w[5..9] (mirror),
// w[10] = mode. Removes the redundant per-thread uniform f64 preamble.
__global__ void temple_setup(const float* __restrict__ x, const float* __restrict__ temple,
                             const float* __restrict__ breath,
                             float* __restrict__ out, double* __restrict__ w) {
    if (threadIdx.x != 0) return;
    double s = 0.0;
    for (int d = 0; d < 5; ++d) s += (double)x[d];
    s = s / 5.0;
    double seed  = s - floor(s);
    double chaos = 3.5699456 * seed * (1.0 - seed);
    int mode = (chaos > 0.7) ? 0 : ((chaos > 0.4) ? 1 : 2);
    for (int d = 0; d < 5; ++d) {
        double a = 0.0, c = 0.0;
        for (int r = 0; r < 4; ++r) {
            double tv = (double)temple[r * 5 + d];
            a += (double)breath[r]     * tv;   // breath_main = breath[0:4]
            c += (double)breath[r + 1] * tv;   // breath_mirror = breath[1:5]
        }
        w[d] = a; w[5 + d] = c;
    }
    w[10] = (double)mode;
    out[GATE_N + EXT_N] = (float)mode;
}

__global__ __launch_bounds__(256) void temple_main(const float* __restrict__ x,
                                                   const double* __restrict__ w,
                                                   float* __restrict__ out) {
    const int k  = threadIdx.x;
    const int b  = blockIdx.x >> 5;            // 32 blocks per b-row
    const int t0 = (blockIdx.x & 31) << 8;     // 256 items per block
    const int mode = (int)w[10];               // uniform scalar load
    const long long rowBase = (long long)b * (2 * T_DIM);
    float* gate = out;
    float* ext  = out + GATE_N;

    // ---- coalesced copy phase: 256 items = 320 float4; wave 0 takes the extra 64 ----
    const float4* __restrict__ src4 = (const float4*)(x + ((long long)b * T_DIM + t0) * 5);
    const bool extra = (k < 64);               // exactly wave 0: no intra-wave divergence
    float4 c0 = src4[k];
    float4 c1;
    if (extra) c1 = src4[256 + k];

    float4* dmain = (float4*)(ext + (rowBase + t0) * 5);
    dmain[k] = c0;
    if (extra) dmain[256 + k] = c1;
    if (mode == 0) {
        float4* dmir = (float4*)(ext + (rowBase + T_DIM + t0) * 5);
        dmir[k] = make_float4(9.f - c0.x, 9.f - c0.y, 9.f - c0.z, 9.f - c0.w);
        if (extra) dmir[256 + k] = make_float4(9.f - c1.x, 9.f - c1.y, 9.f - c1.z, 9.f - c1.w);
    } else if (mode == 2) {
        float4* dmir = (float4*)(ext + (rowBase + T_DIM + t0) * 5);
        dmir[k] = c0;
        if (extra) dmir[256 + k] = c1;
    }

    // ---- this thread's item (L1-hot scalar re-read) ----
    const int t = t0 + k;
    const float* __restrict__ xi = x + ((long long)b * T_DIM + t) * 5;
    const float x0 = xi[0], x1 = xi[1], x2 = xi[2], x3 = xi[3], x4 = xi[4];

    if (mode == 1) {                           // flip: owner writes mirrored address
        float* dm = ext + (rowBase + 2 * T_DIM - 1 - t) * 5;
        dm[0] = x0; dm[1] = x1; dm[2] = x2; dm[3] = x3; dm[4] = x4;
    }

    // ---- two interleaved f64 scan chains (bit-identical math to rounds 1-3) ----
    const double wa0 = w[0], wa1 = w[1], wa2 = w[2], wa3 = w[3], wa4 = w[4];
    const double wb0 = w[5], wb1 = w[6], wb2 = w[7], wb3 = w[8], wb4 = w[9];
    double a0 = x0, a1 = x1, a2 = x2, a3 = x3, a4 = x4;
    double b0, b1, b2, b3, b4;
    if (mode == 0) { b0 = 9.0 - a0; b1 = 9.0 - a1; b2 = 9.0 - a2; b3 = 9.0 - a3; b4 = 9.0 - a4; }
    else           { b0 = a0; b1 = a1; b2 = a2; b3 = a3; b4 = a4; }

    float ha[10], hb[10];
#pragma unroll
    for (int s = 0; s < 10; ++s) {
        double ra = a0 * wa0;
        ra = fma(a1, wa1, ra); ra = fma(a2, wa2, ra); ra = fma(a3, wa3, ra); ra = fma(a4, wa4, ra);
        double rb = b0 * wb0;
        rb = fma(b1, wb1, rb); rb = fma(b2, wb2, rb); rb = fma(b3, wb3, rb); rb = fma(b4, wb4, rb);
        ha[s] = (float)ra; hb[s] = (float)rb;
        double qa = floor(ra * 0.1), ma = fma(qa, -10.0, ra);
        ma = (ma < 0.0) ? ma + 10.0 : ma;  ma = (ma >= 10.0) ? ma - 10.0 : ma;
        double qb = floor(rb * 0.1), mb = fma(qb, -10.0, rb);
        mb = (mb < 0.0) ? mb + 10.0 : mb;  mb = (mb >= 10.0) ? mb - 10.0 : mb;
        a4 = a3; a3 = a2; a2 = a1; a1 = a0; a0 = ma;
        b4 = b3; b3 = b2; b2 = b1; b1 = b0; b0 = mb;
    }
    float meanA = 0.f, meanB = 0.f;
#pragma unroll
    for (int s = 0; s < 10; ++s) { meanA += ha[s]; meanB += hb[s]; }
    meanA *= 0.1f; meanB *= 0.1f;
    float ssdA = 0.f, ssdB = 0.f;
#pragma unroll
    for (int s = 0; s < 10; ++s) {
        float da = ha[s] - meanA; ssdA = fmaf(da, da, ssdA);
        float db = hb[s] - meanB; ssdB = fmaf(db, db, ssdB);
    }
    const float gm = 1.0f / (1.0f + sqrtf(ssdA * (1.0f / 9.0f)));
    const float gx = 1.0f / (1.0f + sqrtf(ssdB * (1.0f / 9.0f)));

    gate[rowBase + t] = gm;
    if (mode == 1) gate[rowBase + 2 * T_DIM - 1 - t] = gx;
    else           gate[rowBase + T_DIM + t] = gx;
}

extern "C" void kernel_launch(void* const* d_in, const int* in_sizes, int n_in,
                              void* d_out, int out_size, void* d_ws, size_t ws_size,
                              hipStream_t stream) {
    const float* x      = (const float*)d_in[0];   // (256, 8192, 5) f32
    const float* temple = (const float*)d_in[1];   // (4, 5) f32
    const float* breath = (const float*)d_in[2];   // (5,) f32
    float* out = (float*)d_out;                    // [gate | extended_x | mode_code]
    double* w  = (double*)d_ws;                    // 11 doubles

    temple_setup<<<1, 64, 0, stream>>>(x, temple, breath, out, w);
    const int blocks = (B_DIM * T_DIM) / 256;      // 8192
    temple_main<<<blocks, 256, 0, stream>>>(x, w, out);
}